// Round 8
// baseline (355.432 us; speedup 1.0000x reference)
//
#include <hip/hip_runtime.h>

typedef __bf16 bf16x8 __attribute__((ext_vector_type(8)));
typedef float  f32x4  __attribute__((ext_vector_type(4)));

// o tile: [96][256] bf16, XOR-swizzled byte layout, 49152 B per 32-pixel tile,
// produced by K1 (scattered 2B stores), consumed by K2 (linear 16B stage -> LDS).
#define OTILE 49152

static __device__ __forceinline__ unsigned short f2b(float f) {
  __bf16 h = (__bf16)f;
  return __builtin_bit_cast(unsigned short, h);
}

__global__ void convert_weights(const float* __restrict__ w_in,
                                const float* __restrict__ w_out,
                                const float* __restrict__ w_conv,
                                __bf16* __restrict__ ws) {
  int gid = blockIdx.x * 256 + threadIdx.x;   // 0..114687
  int i4 = gid * 4;
  const float* src;
  int off;
  if (i4 < 196608)      { src = w_in;   off = i4; }
  else if (i4 < 262144) { src = w_out;  off = i4 - 196608; }
  else                  { src = w_conv; off = i4 - 262144; }
  float4 f = *(const float4*)(src + off);
  ws[i4 + 0] = (__bf16)f.x;
  ws[i4 + 1] = (__bf16)f.y;
  ws[i4 + 2] = (__bf16)f.z;
  ws[i4 + 3] = (__bf16)f.w;
}

// ================= K1: stage x, QKV GEMM, attention; o -> global (swizzled tiles) ===========
__global__ __launch_bounds__(256, 3) void k1_qkv_attn(
    const float* __restrict__ cort,
    const float* __restrict__ subc,
    const float* __restrict__ vent,
    const __bf16* __restrict__ w_in,
    const float* __restrict__ b_in,
    char* __restrict__ o_ws) {
  __shared__ char smem[49152];   // x [96][256] bf16 swz: off=(m*512+2c)^((m&7)<<4)
  const int tid  = threadIdx.x;
  const int lane = tid & 63;
  const int wv   = tid >> 6;
  const int l15  = lane & 15;
  const int l4   = lane >> 4;
  const int blk  = blockIdx.x;
  const int img  = blk >> 7;
  const int pixbase = (blk & 127) << 5;
  const size_t base = (size_t)img * (256 * 4096) + pixbase;

  // stage x -> LDS bf16 swz (128B coalesced reads)
#pragma unroll
  for (int si = 0; si < 3; ++si) {
    const float* rp = (si == 0) ? cort : (si == 1) ? subc : vent;
    rp += base;
#pragma unroll
    for (int t = 0; t < 16; ++t) {
      int idx = t * 256 + tid;
      int p   = idx & 31;
      int c   = (idx >> 5) * 2;
      float f0 = rp[(size_t)c * 4096 + p];
      float f1 = rp[(size_t)(c + 1) * 4096 + p];
      int m = si * 32 + p;
      unsigned off = ((unsigned)(m * 512 + c * 2)) ^ ((unsigned)(m & 7) << 4);
      *(unsigned*)(smem + off) = (unsigned)f2b(f0) | ((unsigned)f2b(f1) << 16);
    }
  }
  __syncthreads();   // only barrier in K1

  char* otile = o_ws + (size_t)blk * OTILE;
  const int ph = wv & 1;
  const int hg = wv >> 1;
  const float SC = 0.17677669529663687f;  // 1/sqrt(32)

  for (int hh = 0; hh < 4; ++hh) {
    const int h = hg * 4 + hh;
    f32x4 acc[3][6] = {};   // [token s][0,1=q 2,3=k 4,5=v]
#pragma unroll
    for (int ks = 0; ks < 8; ++ks) {
      const int k0 = ks * 32;
      bf16x8 af[3];
#pragma unroll
      for (int s = 0; s < 3; ++s) {
        int m = s * 32 + ph * 16 + l15;
        unsigned off = ((unsigned)(m * 512 + (k0 + l4 * 8) * 2)) ^ ((unsigned)(m & 7) << 4);
        af[s] = *(const bf16x8*)(smem + off);
      }
#pragma unroll
      for (int j = 0; j < 6; ++j) {
        int jb = (j >> 1) * 256 + h * 32 + (j & 1) * 16 + l15;
        bf16x8 bfr = *(const bf16x8*)(w_in + (size_t)jb * 256 + k0 + l4 * 8);
#pragma unroll
        for (int s = 0; s < 3; ++s)
          acc[s][j] = __builtin_amdgcn_mfma_f32_16x16x32_bf16(af[s], bfr, acc[s][j], 0, 0, 0);
      }
    }
    // bias (zeros here, kept for generality)
#pragma unroll
    for (int jq = 0; jq < 2; ++jq) {
      float bq = b_in[h * 32 + jq * 16 + l15];
      float bk = b_in[256 + h * 32 + jq * 16 + l15];
      float bv = b_in[512 + h * 32 + jq * 16 + l15];
#pragma unroll
      for (int s = 0; s < 3; ++s)
#pragma unroll
        for (int r = 0; r < 4; ++r) {
          acc[s][jq][r]     += bq;
          acc[s][2 + jq][r] += bk;
          acc[s][4 + jq][r] += bv;
        }
    }
    // in-register attention; lane holds d=jq*16+l15 of pixel p=ph*16+l4*4+r
#pragma unroll
    for (int si = 0; si < 3; ++si) {
      float pp[3][4];
#pragma unroll
      for (int ti = 0; ti < 3; ++ti)
#pragma unroll
        for (int r = 0; r < 4; ++r)
          pp[ti][r] = acc[si][0][r] * acc[ti][2][r] + acc[si][1][r] * acc[ti][3][r];
#pragma unroll
      for (int mask = 1; mask <= 8; mask <<= 1)
#pragma unroll
        for (int ti = 0; ti < 3; ++ti)
#pragma unroll
          for (int r = 0; r < 4; ++r)
            pp[ti][r] += __shfl_xor(pp[ti][r], mask);
#pragma unroll
      for (int r = 0; r < 4; ++r) {
        float s0 = pp[0][r] * SC, s1 = pp[1][r] * SC, s2 = pp[2][r] * SC;
        float mx = fmaxf(fmaxf(s0, s1), s2);
        float e0 = __expf(s0 - mx), e1 = __expf(s1 - mx), e2 = __expf(s2 - mx);
        float inv = 1.f / (e0 + e1 + e2);
        e0 *= inv; e1 *= inv; e2 *= inv;
        int m = si * 32 + ph * 16 + l4 * 4 + r;
#pragma unroll
        for (int jq = 0; jq < 2; ++jq) {
          float ov = e0 * acc[0][4 + jq][r] + e1 * acc[1][4 + jq][r] + e2 * acc[2][4 + jq][r];
          int d = h * 32 + jq * 16 + l15;
          unsigned off = ((unsigned)(m * 512 + d * 2)) ^ ((unsigned)(m & 7) << 4);
          *(__bf16*)(otile + off) = (__bf16)ov;   // fire-and-forget global store
        }
      }
    }
  }
}

// ======= K2: stage o->LDS, out_proj, residual(LN, x from f32), y->LDS, 1x1 conv =======
// LDS: [0,49152) o swz, later y [32][768] swz (o dead after out_proj reads)
//      ps [96][4] f32 @49152, pq @50688, mu @52224, rs @52608  (total 52992)
#define PSOFF 49152
#define PQOFF 50688
#define MUOFF 52224
#define RSOFF 52608

__global__ __launch_bounds__(256, 3) void k2_proj_ln_conv(
    const float* __restrict__ cort,
    const float* __restrict__ subc,
    const float* __restrict__ vent,
    const char* __restrict__ o_ws,
    const __bf16* __restrict__ w_out,
    const float* __restrict__ b_out,
    const float* __restrict__ gamma,
    const float* __restrict__ beta,
    const __bf16* __restrict__ w_conv,
    const float* __restrict__ b_conv,
    float* __restrict__ out) {
  __shared__ char smem[52992];
  const int tid  = threadIdx.x;
  const int lane = tid & 63;
  const int wv   = tid >> 6;
  const int l15  = lane & 15;
  const int l4   = lane >> 4;
  const int blk  = blockIdx.x;
  const int img  = blk >> 7;
  const int pixbase = (blk & 127) << 5;
  const size_t base = (size_t)img * (256 * 4096) + pixbase;

  // stage o tile (pre-swizzled in global) -> LDS, linear 16B copies
  {
    const char* src = o_ws + (size_t)blk * OTILE;
#pragma unroll
    for (int t = 0; t < 12; ++t) {
      int off = t * 4096 + tid * 16;
      *(bf16x8*)(smem + off) = *(const bf16x8*)(src + off);
    }
  }
  __syncthreads();   // B1

  // out_proj: y = o @ w_out^T; wave owns 64 N-cols, all 96 rows
  f32x4 accY[6][4] = {};
#pragma unroll
  for (int ks = 0; ks < 8; ++ks) {
    const int k0 = ks * 32;
    bf16x8 af[6], bfr[4];
#pragma unroll
    for (int i = 0; i < 6; ++i) {
      int m = i * 16 + l15;
      unsigned off = ((unsigned)(m * 512 + (k0 + l4 * 8) * 2)) ^ ((unsigned)(m & 7) << 4);
      af[i] = *(const bf16x8*)(smem + off);
    }
#pragma unroll
    for (int j = 0; j < 4; ++j) {
      int jr = wv * 64 + j * 16 + l15;
      bfr[j] = *(const bf16x8*)(w_out + (size_t)jr * 256 + k0 + l4 * 8);
    }
#pragma unroll
    for (int i = 0; i < 6; ++i)
#pragma unroll
      for (int j = 0; j < 4; ++j)
        accY[i][j] = __builtin_amdgcn_mfma_f32_16x16x32_bf16(af[i], bfr[j], accY[i][j], 0, 0, 0);
  }

  // bias + residual (x re-read from f32 global, L3-hot) + LN partials
  float bo[4], gg[4], bb[4];
#pragma unroll
  for (int j = 0; j < 4; ++j) {
    int jc = wv * 64 + j * 16 + l15;
    bo[j] = b_out[jc];
    gg[j] = gamma[jc];
    bb[j] = beta[jc];
  }
#pragma unroll
  for (int i = 0; i < 6; ++i) {
    const float* rp = ((i >> 1) == 0) ? cort : ((i >> 1) == 1) ? subc : vent;
#pragma unroll
    for (int r = 0; r < 4; ++r) {
      int m = i * 16 + l4 * 4 + r;
      int p = m & 31;
      float s1 = 0.f, s2 = 0.f;
#pragma unroll
      for (int j = 0; j < 4; ++j) {
        int jc = wv * 64 + j * 16 + l15;
        float xv = rp[base + (size_t)jc * 4096 + p];
        float v = accY[i][j][r] + bo[j] + xv;
        accY[i][j][r] = v;
        s1 += v;
        s2 += v * v;
      }
      s1 += __shfl_xor(s1, 1); s2 += __shfl_xor(s2, 1);
      s1 += __shfl_xor(s1, 2); s2 += __shfl_xor(s2, 2);
      s1 += __shfl_xor(s1, 4); s2 += __shfl_xor(s2, 4);
      s1 += __shfl_xor(s1, 8); s2 += __shfl_xor(s2, 8);
      if (l15 == 0) {
        *(float*)(smem + PSOFF + (m * 4 + wv) * 4) = s1;
        *(float*)(smem + PQOFF + (m * 4 + wv) * 4) = s2;
      }
    }
  }
  __syncthreads();   // B2 (also: all o reads complete)
  if (tid < 96) {
    float s = 0.f, q = 0.f;
#pragma unroll
    for (int j = 0; j < 4; ++j) {
      s += *(const float*)(smem + PSOFF + (tid * 4 + j) * 4);
      q += *(const float*)(smem + PQOFF + (tid * 4 + j) * 4);
    }
    float mu  = s * (1.f / 256.f);
    float var = q * (1.f / 256.f) - mu * mu;
    *(float*)(smem + MUOFF + tid * 4) = mu;
    *(float*)(smem + RSOFF + tid * 4) = rsqrtf(var + 1e-5f);
  }
  __syncthreads();   // B3
  // rescale + write y bf16 [32][768] swz into region 0 (o is dead)
#pragma unroll
  for (int i = 0; i < 6; ++i)
#pragma unroll
    for (int r = 0; r < 4; ++r) {
      int m = i * 16 + l4 * 4 + r;
      float mu = *(const float*)(smem + MUOFF + m * 4);
      float rs = *(const float*)(smem + RSOFF + m * 4);
      int s = m >> 5, p = m & 31;
#pragma unroll
      for (int j = 0; j < 4; ++j) {
        int jc = wv * 64 + j * 16 + l15;
        float yv = (accY[i][j][r] - mu) * rs * gg[j] + bb[j];
        int kk = s * 256 + jc;
        unsigned off = ((unsigned)(p * 1536 + kk * 2)) ^ ((unsigned)(p & 7) << 4);
        *(__bf16*)(smem + off) = (__bf16)yv;
      }
    }
  __syncthreads();   // B4

  // 1x1 conv: M=cout(256, wave owns 64), N=pixel(32), K=768
  {
    f32x4 accC[4][2] = {};
#pragma unroll 4
    for (int ks = 0; ks < 24; ++ks) {
      const int k0 = ks * 32;
      bf16x8 af[4], bfr2[2];
#pragma unroll
      for (int i = 0; i < 4; ++i) {
        int co = wv * 64 + i * 16 + l15;
        af[i] = *(const bf16x8*)(w_conv + (size_t)co * 768 + k0 + l4 * 8);
      }
#pragma unroll
      for (int j = 0; j < 2; ++j) {
        int p = j * 16 + l15;
        unsigned off = ((unsigned)(p * 1536 + (k0 + l4 * 8) * 2)) ^ ((unsigned)(p & 7) << 4);
        bfr2[j] = *(const bf16x8*)(smem + off);
      }
#pragma unroll
      for (int i = 0; i < 4; ++i)
#pragma unroll
        for (int j = 0; j < 2; ++j)
          accC[i][j] = __builtin_amdgcn_mfma_f32_16x16x32_bf16(af[i], bfr2[j], accC[i][j], 0, 0, 0);
    }
#pragma unroll
    for (int i = 0; i < 4; ++i)
#pragma unroll
      for (int r = 0; r < 4; ++r) {
        int co = wv * 64 + i * 16 + l4 * 4 + r;
        float cb = b_conv[co];
#pragma unroll
        for (int j = 0; j < 2; ++j)
          out[((size_t)img * 256 + co) * 4096 + pixbase + j * 16 + l15] = accC[i][j][r] + cb;
      }
  }
}

extern "C" void kernel_launch(void* const* d_in, const int* in_sizes, int n_in,
                              void* d_out, int out_size, void* d_ws, size_t ws_size,
                              hipStream_t stream) {
  (void)in_sizes; (void)n_in; (void)out_size; (void)ws_size;
  const float* cort    = (const float*)d_in[0];
  const float* subc    = (const float*)d_in[1];
  const float* vent    = (const float*)d_in[2];
  const float* w_in_f  = (const float*)d_in[3];
  const float* b_in    = (const float*)d_in[4];
  const float* w_out_f = (const float*)d_in[5];
  const float* b_out   = (const float*)d_in[6];
  const float* gamma   = (const float*)d_in[7];
  const float* beta    = (const float*)d_in[8];
  const float* w_conv_f= (const float*)d_in[9];
  const float* b_conv  = (const float*)d_in[10];

  __bf16* wsb = (__bf16*)d_ws;                       // weights: 917504 B
  char*   o_ws = (char*)d_ws + (1 << 20);            // o: 1024 * 49152 = 50331648 B (needs ws >= ~52 MB)

  convert_weights<<<448, 256, 0, stream>>>(w_in_f, w_out_f, w_conv_f, wsb);
  k1_qkv_attn<<<1024, 256, 0, stream>>>(cort, subc, vent, wsb, b_in, o_ws);
  k2_proj_ln_conv<<<1024, 256, 0, stream>>>(cort, subc, vent, o_ws,
                                            wsb + 196608, b_out, gamma, beta,
                                            wsb + 262144, b_conv, (float*)d_out);
}